// Round 9
// baseline (613.168 us; speedup 1.0000x reference)
//
#include <hip/hip_runtime.h>
#include <hip/hip_bf16.h>
#include <stdint.h>
#include <math.h>

#define NPTS 2048
#define BSZ 8
#define KNN 16
#define MROWS (BSZ * NPTS)   // 16384

typedef __attribute__((ext_vector_type(8))) short bf16x8;
typedef __attribute__((ext_vector_type(4))) float f32x4;

__device__ __forceinline__ unsigned short f2bf(float f) {
    __hip_bfloat16 h = __float2bfloat16(f);
    return *(unsigned short*)&h;
}
__device__ __forceinline__ float bf2f(unsigned short u) {
    return __uint_as_float(((unsigned)u) << 16);
}

// ---------- helpers ----------
__device__ __forceinline__ unsigned sortable32(float f) {
    unsigned u = __float_as_uint(f);
    return u ^ ((unsigned)((int)u >> 31) | 0x80000000u);
}

__device__ __forceinline__ void cas_asc(unsigned long long &a, unsigned long long &b) {
    unsigned long long lo = a < b ? a : b;
    unsigned long long hi = a < b ? b : a;
    a = lo; b = hi;
}

__device__ __forceinline__ void sort16u(unsigned long long k[16]) {
    #pragma unroll
    for (int kk = 2; kk <= 16; kk <<= 1) {
        #pragma unroll
        for (int j = kk >> 1; j > 0; j >>= 1) {
            #pragma unroll
            for (int i = 0; i < 16; ++i) {
                const int l = i ^ j;
                if (l > i) {
                    if ((i & kk) == 0) cas_asc(k[i], k[l]);
                    else               cas_asc(k[l], k[i]);
                }
            }
        }
    }
}

__device__ __forceinline__ void clean16u(unsigned long long k[16]) {
    #pragma unroll
    for (int j = 8; j > 0; j >>= 1) {
        #pragma unroll
        for (int i = 0; i < 16; ++i) {
            const int l = i ^ j;
            if (l > i) cas_asc(k[i], k[l]);
        }
    }
}

// ---------- KNN + covariance (+ folded w_gl2 conversion blocks) ----------
__global__ __launch_bounds__(256)
void knn_cov_kernel(const float* __restrict__ x, const int* __restrict__ mask,
                    int* __restrict__ idx_out, float* __restrict__ h0,
                    const float* __restrict__ w_gl2,
                    unsigned short* __restrict__ wTh, unsigned short* __restrict__ wTl)
{
    const int tid = threadIdx.x;
    if (blockIdx.x >= 4096) {
        const int t = (blockIdx.x - 4096) * 256 + tid;   // t = n*128 + k
        const int n = t >> 7, k = t & 127;
        const float v = w_gl2[(size_t)k * 1024 + n];
        const unsigned short hi = f2bf(v);
        wTh[t] = hi;
        wTl[t] = f2bf(v - bf2f(hi));
        return;
    }

    __shared__ float4 cand[NPTS];
    const int wave = tid >> 6;
    const int lane = tid & 63;
    const int b = blockIdx.x >> 9;
    const int q = ((blockIdx.x & 511) << 2) + wave;
    const float* xb = x + (size_t)b * 3 * NPTS;
    const int*   mb = mask + b * NPTS;

    for (int m = tid; m < NPTS; m += 256) {
        float px = xb[m], py = xb[NPTS + m], pz = xb[2 * NPTS + m];
        float sq = px * px + py * py + pz * pz;
        if (mb[m] != 1) sq = INFINITY;
        cand[m] = make_float4(px, py, pz, sq);
    }
    __syncthreads();

    const float4 qc = cand[q];
    const float qx = qc.x, qy = qc.y, qz = qc.z;
    const float sqn = qx * qx + qy * qy + qz * qz;

    unsigned long long ld[16];
    #pragma unroll
    for (int t = 0; t < 16; ++t) {
        const int m = t * 64 + lane;
        const float4 c = cand[m];
        const float d = fmaf(-2.f, qx * c.x + qy * c.y + qz * c.z, sqn + c.w);
        ld[t] = ((unsigned long long)sortable32(d) << 32) | (unsigned)m;
    }
    sort16u(ld);

    unsigned long long cb[16];
    #pragma unroll
    for (int t = 0; t < 16; ++t) {
        const int m = (16 + t) * 64 + lane;
        const float4 c = cand[m];
        const float d = fmaf(-2.f, qx * c.x + qy * c.y + qz * c.z, sqn + c.w);
        cb[t] = ((unsigned long long)sortable32(d) << 32) | (unsigned)m;
    }
    sort16u(cb);

    {
        unsigned long long mg[16];
        #pragma unroll
        for (int i = 0; i < 16; ++i) {
            const unsigned long long a = ld[i], b2 = cb[15 - i];
            mg[i] = a < b2 ? a : b2;
        }
        clean16u(mg);
        #pragma unroll
        for (int i = 0; i < 16; ++i) ld[i] = mg[i];
    }

    #pragma unroll
    for (int p = 1; p <= 32; p <<= 1) {
        unsigned long long c2[16];
        #pragma unroll
        for (int i = 0; i < 16; ++i) {
            const unsigned long long pr = __shfl_xor(ld[15 - i], p, 64);
            c2[i] = ld[i] < pr ? ld[i] : pr;
        }
        clean16u(c2);
        #pragma unroll
        for (int i = 0; i < 16; ++i) ld[i] = c2[i];
    }

    const int gq = b * NPTS + q;
    if (lane < KNN)
        idx_out[gq * KNN + lane] = b * NPTS + (int)(unsigned)ld[lane];

    const int ml = (int)(unsigned)ld[lane & 15];
    const float4 nb = cand[ml];
    float sx = nb.x, sy = nb.y, sz = nb.z;
    #pragma unroll
    for (int m = 1; m < 16; m <<= 1) {
        sx += __shfl_xor(sx, m, 64); sy += __shfl_xor(sy, m, 64); sz += __shfl_xor(sz, m, 64);
    }
    const float mx = sx * 0.0625f, my = sy * 0.0625f, mz = sz * 0.0625f;
    const float cx = nb.x - mx, cy = nb.y - my, cz = nb.z - mz;
    float xx = cx * cx, xy = cx * cy, xz = cx * cz;
    float yy = cy * cy, yz = cy * cz, zz = cz * cz;
    #pragma unroll
    for (int m = 1; m < 16; m <<= 1) {
        xx += __shfl_xor(xx, m, 64); xy += __shfl_xor(xy, m, 64); xz += __shfl_xor(xz, m, 64);
        yy += __shfl_xor(yy, m, 64); yz += __shfl_xor(yz, m, 64); zz += __shfl_xor(zz, m, 64);
    }
    if (lane == 0) {
        float* o = h0 + (size_t)gq * 12;
        o[0] = qx; o[1] = qy; o[2] = qz;
        o[3] = xx; o[4] = xy; o[5] = xz;
        o[6] = xy; o[7] = yy; o[8] = yz;
        o[9] = xz; o[10] = yz; o[11] = zz;
    }
}

// ---------- broadcast GEMM for skinny K (K<=64, C in {64,128}) ----------
// Lane owns one output column (W column in regs); X row broadcast via readlane.
// Optional BN+ReLU fold on X (k = lane -> per-lane constant scale/shift).
// Writes per-block stats chunk (grid = 1024 chunks).
template<int K, int C>
__global__ __launch_bounds__(256)
void bgemm_kernel(const float* __restrict__ X, const float* __restrict__ W,
                  const float* __restrict__ bias,
                  const float* __restrict__ xsc, const float* __restrict__ xsh,
                  float* __restrict__ Y, float* __restrict__ ops, float* __restrict__ opss)
{
    constexpr int NWC = C / 64;       // waves covering columns
    constexpr int NWR = 4 / NWC;      // row streams
    constexpr int RPB = 16;           // rows per block
    constexpr int RPW = RPB / NWR;
    const int tid = threadIdx.x, wave = tid >> 6, lane = tid & 63;
    const int wr = wave / NWC, wc = wave % NWC;
    const int col = wc * 64 + lane;

    float wreg[K];
    #pragma unroll
    for (int k = 0; k < K; ++k) wreg[k] = W[(size_t)k * C + col];
    const float bv = bias[col];

    const bool bnx = (xsc != nullptr);
    float ksc = 0.f, ksh = 0.f;
    if (bnx && lane < K) { ksc = xsc[lane]; ksh = xsh[lane]; }

    float s = 0.f, ss = 0.f;
    const int row0 = blockIdx.x * RPB + wr * RPW;
    for (int r = 0; r < RPW; ++r) {
        const int row = row0 + r;
        float xv = (lane < K) ? X[(size_t)row * K + lane] : 0.f;
        if (bnx) xv = fmaxf(0.f, fmaf(xv, ksc, ksh));
        float acc = 0.f;
        #pragma unroll
        for (int k = 0; k < K; ++k) {
            const float xk = __uint_as_float(
                (unsigned)__builtin_amdgcn_readlane((int)__float_as_uint(xv), k));
            acc = fmaf(xk, wreg[k], acc);
        }
        const float yv = acc + bv;
        Y[(size_t)row * C + col] = yv;
        s += yv; ss = fmaf(yv, yv, ss);
    }

    __shared__ float red[4][64], red2[4][64];
    red[wave][lane] = s; red2[wave][lane] = ss;
    __syncthreads();
    if (tid < C) {
        float S = 0.f, SS = 0.f;
        #pragma unroll
        for (int w2 = 0; w2 < NWR; ++w2) {
            const int widx = w2 * NWC + (tid >> 6);
            S += red[widx][tid & 63]; SS += red2[widx][tid & 63];
        }
        ops[(size_t)blockIdx.x * C + tid] = S;
        opss[(size_t)blockIdx.x * C + tid] = SS;
    }
}

// ---------- stats finalize: chunks -> scale/shift (+optional pooled zero) ----------
template<int C, int PARTS>
__global__ void stats_final(const float* __restrict__ ps, const float* __restrict__ pss,
                            const float* __restrict__ g, const float* __restrict__ be,
                            float* __restrict__ sc, float* __restrict__ sh,
                            float* __restrict__ pooled, int nch)
{
    __shared__ float r1[256], r2[256];
    const int tid = threadIdx.x;
    const int c = blockIdx.x * 256 + (tid % C);
    const int part = tid / C;
    const int per = nch / PARTS;
    float s = 0.f, ss = 0.f;
    for (int i = part * per; i < (part + 1) * per; ++i) {
        s += ps[(size_t)i * C + c]; ss += pss[(size_t)i * C + c];
    }
    if (PARTS > 1) {
        r1[tid] = s; r2[tid] = ss;
        __syncthreads();
        if (part == 0) {
            #pragma unroll
            for (int w = 1; w < PARTS; ++w) { s += r1[tid + w * C]; ss += r2[tid + w * C]; }
        }
    }
    if (part == 0) {
        if (pooled) {
            #pragma unroll
            for (int b = 0; b < 8; ++b) pooled[b * C + c] = 0.f;
        }
        const float invM = 1.f / (float)MROWS;
        const float mean = s * invM;
        const float var = fmaxf(ss * invM - mean * mean, 0.f);
        const float scv = g[c] * rsqrtf(var + 1e-5f);
        sc[c] = scv;
        sh[c] = be[c] - mean * scv;
    }
}

// ---------- gl2 MFMA GEMM (split-bf16, 3 passes) + fused psum chunks ----------
__global__ __launch_bounds__(256)
void gemm_gl2_mfma(const unsigned short* __restrict__ Ahi, const unsigned short* __restrict__ Alo,
                   const unsigned short* __restrict__ Whi, const unsigned short* __restrict__ Wlo,
                   const float* __restrict__ bias, float* __restrict__ Y,
                   float* __restrict__ ops, float* __restrict__ opss)
{
    __shared__ float ps[2][128], pss2[2][128];
    const int wave = threadIdx.x >> 6, lane = threadIdx.x & 63;
    const int wm = wave >> 1, wn = wave & 1;
    const int bm = blockIdx.x * 128 + wm * 64;
    const int bn = blockIdx.y * 128 + wn * 64;
    const int lrow = lane & 15;
    const int lk = (lane >> 4) * 8;
    f32x4 acc[4][4] = {};
    #pragma unroll
    for (int ks = 0; ks < 4; ++ks) {
        const int k0 = ks * 32 + lk;
        bf16x8 ah[4], al[4], bh[4], bl[4];
        #pragma unroll
        for (int mf = 0; mf < 4; ++mf) {
            const size_t off = (size_t)(bm + mf * 16 + lrow) * 128 + k0;
            ah[mf] = *(const bf16x8*)(Ahi + off);
            al[mf] = *(const bf16x8*)(Alo + off);
        }
        #pragma unroll
        for (int nf = 0; nf < 4; ++nf) {
            const size_t off = (size_t)(bn + nf * 16 + lrow) * 128 + k0;
            bh[nf] = *(const bf16x8*)(Whi + off);
            bl[nf] = *(const bf16x8*)(Wlo + off);
        }
        #pragma unroll
        for (int mf = 0; mf < 4; ++mf)
            #pragma unroll
            for (int nf = 0; nf < 4; ++nf) {
                acc[mf][nf] = __builtin_amdgcn_mfma_f32_16x16x32_bf16(ah[mf], bh[nf], acc[mf][nf], 0, 0, 0);
                acc[mf][nf] = __builtin_amdgcn_mfma_f32_16x16x32_bf16(ah[mf], bl[nf], acc[mf][nf], 0, 0, 0);
                acc[mf][nf] = __builtin_amdgcn_mfma_f32_16x16x32_bf16(al[mf], bh[nf], acc[mf][nf], 0, 0, 0);
            }
    }
    const int r0 = (lane >> 4) * 4, cc = lane & 15;
    float s[4] = {0.f, 0.f, 0.f, 0.f}, sq2[4] = {0.f, 0.f, 0.f, 0.f};
    #pragma unroll
    for (int mf = 0; mf < 4; ++mf) {
        const int row = bm + mf * 16 + r0;
        #pragma unroll
        for (int nf = 0; nf < 4; ++nf) {
            const int col = bn + nf * 16 + cc;
            const float bv = bias[col];
            #pragma unroll
            for (int r = 0; r < 4; ++r) {
                const float yv = acc[mf][nf][r] + bv;
                Y[(size_t)(row + r) * 1024 + col] = yv;
                s[nf] += yv; sq2[nf] = fmaf(yv, yv, sq2[nf]);
            }
        }
    }
    #pragma unroll
    for (int nf = 0; nf < 4; ++nf) {
        #pragma unroll
        for (int off = 16; off < 64; off <<= 1) {
            s[nf]   += __shfl_xor(s[nf], off, 64);
            sq2[nf] += __shfl_xor(sq2[nf], off, 64);
        }
    }
    if (lane < 16) {
        #pragma unroll
        for (int nf = 0; nf < 4; ++nf) {
            ps[wm][wn * 64 + nf * 16 + lane] = s[nf];
            pss2[wm][wn * 64 + nf * 16 + lane] = sq2[nf];
        }
    }
    __syncthreads();
    if (threadIdx.x < 128) {
        const size_t o = (size_t)blockIdx.x * 1024 + blockIdx.y * 128 + threadIdx.x;
        ops[o]  = ps[0][threadIdx.x] + ps[1][threadIdx.x];
        opss[o] = pss2[0][threadIdx.x] + pss2[1][threadIdx.x];
    }
}

// ---------- gather-max + BN(scale/shift direct), 64 ch ----------
__global__ __launch_bounds__(256)
void gathermax_bn64(const float* __restrict__ Hin, const int* __restrict__ idxmat,
                    const float* __restrict__ scv, const float* __restrict__ shv,
                    float* __restrict__ Z)
{
    const int c4 = threadIdx.x & 15, rr = threadIdx.x >> 4;
    const int row = (blockIdx.x << 4) + rr;
    const int* ip = idxmat + (size_t)row * KNN;
    const float4 sc = ((const float4*)scv)[c4], sh = ((const float4*)shv)[c4];
    float4 m = {0.f, 0.f, 0.f, 0.f};
    #pragma unroll
    for (int k = 0; k < KNN; ++k) {
        const int j = ip[k];
        const float4 v = *(const float4*)(Hin + (size_t)j * 64 + c4 * 4);
        m.x = fmaxf(m.x, fmaf(v.x, sc.x, sh.x));
        m.y = fmaxf(m.y, fmaf(v.y, sc.y, sh.y));
        m.z = fmaxf(m.z, fmaf(v.z, sc.z, sh.z));
        m.w = fmaxf(m.w, fmaf(v.w, sc.w, sh.w));
    }
    ((float4*)(Z + (size_t)row * 64))[c4] = m;
}

// ---------- gather-max + BN(direct), 128 ch, split-bf16 out ----------
__global__ __launch_bounds__(256)
void gathermax_bn128_split(const float* __restrict__ Hin, const int* __restrict__ idxmat,
                           const float* __restrict__ scv, const float* __restrict__ shv,
                           unsigned short* __restrict__ Zhi, unsigned short* __restrict__ Zlo)
{
    const int c4 = threadIdx.x & 31, rr = threadIdx.x >> 5;
    const int row = (blockIdx.x << 3) + rr;
    const int* ip = idxmat + (size_t)row * KNN;
    const float4 sc = ((const float4*)scv)[c4], sh = ((const float4*)shv)[c4];
    float4 m = {0.f, 0.f, 0.f, 0.f};
    #pragma unroll
    for (int k = 0; k < KNN; ++k) {
        const int j = ip[k];
        const float4 v = *(const float4*)(Hin + (size_t)j * 128 + c4 * 4);
        m.x = fmaxf(m.x, fmaf(v.x, sc.x, sh.x));
        m.y = fmaxf(m.y, fmaf(v.y, sc.y, sh.y));
        m.z = fmaxf(m.z, fmaf(v.z, sc.z, sh.z));
        m.w = fmaxf(m.w, fmaf(v.w, sc.w, sh.w));
    }
    ushort4 hi, lo;
    hi.x = f2bf(m.x); lo.x = f2bf(m.x - bf2f(hi.x));
    hi.y = f2bf(m.y); lo.y = f2bf(m.y - bf2f(hi.y));
    hi.z = f2bf(m.z); lo.z = f2bf(m.z - bf2f(hi.z));
    hi.w = f2bf(m.w); lo.w = f2bf(m.w - bf2f(hi.w));
    *(ushort4*)(Zhi + (size_t)row * 128 + c4 * 4) = hi;
    *(ushort4*)(Zlo + (size_t)row * 128 + c4 * 4) = lo;
}

// ---------- fused bnrelu + masked segment max, fp32 ----------
__global__ __launch_bounds__(256)
void segmax_bnrelu_f32(const float* __restrict__ Y, const float* __restrict__ scale,
                       const float* __restrict__ shift, const int* __restrict__ mask,
                       unsigned* __restrict__ pooled)
{
    __shared__ int mk[64];
    const int b = blockIdx.x, nc = blockIdx.y;
    const int n0 = nc * 64;
    if (threadIdx.x < 64) mk[threadIdx.x] = mask[b * NPTS + n0 + threadIdx.x];
    __syncthreads();
    const int c4 = threadIdx.x;
    const float4 sc = ((const float4*)scale)[c4], sh = ((const float4*)shift)[c4];
    float4 m = {0.f, 0.f, 0.f, 0.f};
    for (int n = 0; n < 64; ++n) {
        if (mk[n]) {
            const float4 v = ((const float4*)(Y + ((size_t)b * NPTS + n0 + n) * 1024))[c4];
            m.x = fmaxf(m.x, fmaf(v.x, sc.x, sh.x));
            m.y = fmaxf(m.y, fmaf(v.y, sc.y, sh.y));
            m.z = fmaxf(m.z, fmaf(v.z, sc.z, sh.z));
            m.w = fmaxf(m.w, fmaf(v.w, sc.w, sh.w));
        }
    }
    m.x = fmaxf(m.x, 0.f); m.y = fmaxf(m.y, 0.f); m.z = fmaxf(m.z, 0.f); m.w = fmaxf(m.w, 0.f);
    atomicMax(&pooled[b * 1024 + c4 * 4 + 0], __float_as_uint(m.x));
    atomicMax(&pooled[b * 1024 + c4 * 4 + 1], __float_as_uint(m.y));
    atomicMax(&pooled[b * 1024 + c4 * 4 + 2], __float_as_uint(m.z));
    atomicMax(&pooled[b * 1024 + c4 * 4 + 3], __float_as_uint(m.w));
}

// ---------- head: 8-row GEMM + BN(8) + ReLU; 64 blocks x 8 cols, 32-way K-split ----------
template<int KDIM>
__global__ __launch_bounds__(256)
void mlp8_kernel(const float* __restrict__ In, const float* __restrict__ W,
                 const float* __restrict__ bias, const float* __restrict__ g,
                 const float* __restrict__ be, float* __restrict__ Out)
{
    __shared__ float Ins[8 * KDIM];
    __shared__ float part[32][8][8];
    __shared__ float ys[8][8];
    const int tid = threadIdx.x;
    for (int e = tid; e < 8 * KDIM; e += 256) Ins[e] = In[e];
    __syncthreads();
    const int c = tid & 7, kp = tid >> 3;
    const int col = (blockIdx.x << 3) + c;
    constexpr int KS = KDIM / 32;
    float a[8] = {};
    for (int k = kp * KS; k < (kp + 1) * KS; ++k) {
        const float w = W[(size_t)k * 512 + col];
        #pragma unroll
        for (int r = 0; r < 8; ++r) a[r] = fmaf(Ins[r * KDIM + k], w, a[r]);
    }
    #pragma unroll
    for (int r = 0; r < 8; ++r) part[kp][r][c] = a[r];
    __syncthreads();
    if (tid < 64) {
        const int r = tid >> 3, cc = tid & 7;
        float s = 0.f;
        #pragma unroll
        for (int p = 0; p < 32; ++p) s += part[p][r][cc];
        ys[r][cc] = s + bias[(blockIdx.x << 3) + cc];
    }
    __syncthreads();
    if (tid < 8) {
        const int c2 = (blockIdx.x << 3) + tid;
        float s = 0.f, ss = 0.f;
        #pragma unroll
        for (int r = 0; r < 8; ++r) { const float v = ys[r][tid]; s += v; ss = fmaf(v, v, ss); }
        const float mean = s * 0.125f;
        const float var = fmaxf(ss * 0.125f - mean * mean, 0.f);
        const float sc = g[c2] * rsqrtf(var + 1e-5f);
        const float sh = be[c2] - mean * sc;
        #pragma unroll
        for (int r = 0; r < 8; ++r)
            Out[r * 512 + c2] = fmaxf(0.f, fmaf(ys[r][tid], sc, sh));
    }
}

// ---------- launcher ----------
extern "C" void kernel_launch(void* const* d_in, const int* in_sizes, int n_in,
                              void* d_out, int out_size, void* d_ws, size_t ws_size,
                              hipStream_t stream)
{
    const float* x    = (const float*)d_in[0];
    const int*   mask = (const int*)d_in[1];
    const float* w_m1a = (const float*)d_in[2];
    const float* b_m1a = (const float*)d_in[3];
    const float* g_m1a = (const float*)d_in[4];
    const float* be_m1a = (const float*)d_in[5];
    const float* w_m1b = (const float*)d_in[6];
    const float* b_m1b = (const float*)d_in[7];
    const float* g_m1b = (const float*)d_in[8];
    const float* be_m1b = (const float*)d_in[9];
    const float* w_m1c = (const float*)d_in[10];
    const float* b_m1c = (const float*)d_in[11];
    const float* g_m1c = (const float*)d_in[12];
    const float* be_m1c = (const float*)d_in[13];
    const float* w_gl1 = (const float*)d_in[14];
    const float* b_gl1 = (const float*)d_in[15];
    const float* g_gl1 = (const float*)d_in[16];
    const float* be_gl1 = (const float*)d_in[17];
    const float* w_gl2 = (const float*)d_in[18];
    const float* b_gl2 = (const float*)d_in[19];
    const float* g_gl2 = (const float*)d_in[20];
    const float* be_gl2 = (const float*)d_in[21];
    const float* w_m2a = (const float*)d_in[22];
    const float* b_m2a = (const float*)d_in[23];
    const float* g_m2a = (const float*)d_in[24];
    const float* be_m2a = (const float*)d_in[25];
    const float* w_m2b = (const float*)d_in[26];
    const float* b_m2b = (const float*)d_in[27];
    const float* g_m2b = (const float*)d_in[28];
    const float* be_m2b = (const float*)d_in[29];

    float* ws = (float*)d_ws;
    int*   idx  = (int*)ws;                              // +262144
    float* h0   = ws + 262144;                           // +196608
    float* bufA = ws + 458752;                           // +1048576
    float* bufB = ws + 1507328;                          // +1048576
    float* bufC = ws + 2555904;                          // +2097152
    unsigned short* wTh = (unsigned short*)(ws + 4653056);   // +65536
    unsigned short* wTl = (unsigned short*)(ws + 4718592);   // +65536
    float* bufE  = ws + 4784128;                         // +16777216
    float* pooled = ws + 21561344;                       // +8192
    float* y1     = ws + 21569536;                       // +4096
    float* ps0    = ws + 21573632;                       // +131072
    float* pss0   = ws + 21704704;                       // +131072
    float* ps1    = ws + 21835776;                       // +131072
    float* pss1   = ws + 21966848;                       // +131072
    float* scale  = ws + 22097920;                       // +1024
    float* shift  = ws + 22098944;                       // +1024

    unsigned short* Ahi = (unsigned short*)bufA;
    unsigned short* Alo = (unsigned short*)bufB;

    // knn + folded w_gl2 conversion
    knn_cov_kernel<<<4608, 256, 0, stream>>>(x, mask, idx, h0, w_gl2, wTh, wTl);

    // m1a: 12 -> 64
    bgemm_kernel<12, 64><<<1024, 256, 0, stream>>>(
        h0, w_m1a, b_m1a, nullptr, nullptr, bufA, ps0, pss0);
    stats_final<64, 4><<<1, 256, 0, stream>>>(ps0, pss0, g_m1a, be_m1a, scale, shift, nullptr, 1024);

    // m1b: 64 -> 64 (bn_m1a folded at X load)
    bgemm_kernel<64, 64><<<1024, 256, 0, stream>>>(
        bufA, w_m1b, b_m1b, scale, shift, bufB, ps1, pss1);
    stats_final<64, 4><<<1, 256, 0, stream>>>(ps1, pss1, g_m1b, be_m1b, scale, shift, nullptr, 1024);

    // m1c: 64 -> 64 (bn_m1b folded)
    bgemm_kernel<64, 64><<<1024, 256, 0, stream>>>(
        bufB, w_m1c, b_m1c, scale, shift, bufA, ps0, pss0);
    stats_final<64, 4><<<1, 256, 0, stream>>>(ps0, pss0, g_m1c, be_m1c, scale, shift, nullptr, 1024);

    // gather-max 64 (bn_m1c direct)
    gathermax_bn64<<<1024, 256, 0, stream>>>(bufA, idx, scale, shift, bufB);

    // gl1: 64 -> 128
    bgemm_kernel<64, 128><<<1024, 256, 0, stream>>>(
        bufB, w_gl1, b_gl1, nullptr, nullptr, bufC, ps1, pss1);
    stats_final<128, 2><<<1, 256, 0, stream>>>(ps1, pss1, g_gl1, be_gl1, scale, shift, nullptr, 1024);

    // gather-max 128 (bn_gl1 direct) -> split-bf16 A
    gathermax_bn128_split<<<2048, 256, 0, stream>>>(bufC, idx, scale, shift, Ahi, Alo);

    // gl2: 128 -> 1024, split-bf16 MFMA + fused stats chunks
    gemm_gl2_mfma<<<dim3(128, 8), 256, 0, stream>>>(Ahi, Alo, wTh, wTl, b_gl2, bufE, ps0, pss0);
    stats_final<1024, 1><<<4, 256, 0, stream>>>(ps0, pss0, g_gl2, be_gl2, scale, shift, pooled, 128);

    // fused bnrelu + masked segment-max
    segmax_bnrelu_f32<<<dim3(8, 32), 256, 0, stream>>>(bufE, scale, shift, mask, (unsigned*)pooled);

    // head
    mlp8_kernel<1024><<<64, 256, 0, stream>>>(pooled, w_m2a, b_m2a, g_m2a, be_m2a, y1);
    mlp8_kernel<512><<<64, 256, 0, stream>>>(y1, w_m2b, b_m2b, g_m2b, be_m2b, (float*)d_out);
}

// Round 10
// 235.572 us; speedup vs baseline: 2.6029x; 2.6029x over previous
//
#include <hip/hip_runtime.h>
#include <hip/hip_bf16.h>
#include <stdint.h>
#include <math.h>

#define NPTS 2048
#define BSZ 8
#define KNN 16
#define MROWS (BSZ * NPTS)   // 16384

typedef __attribute__((ext_vector_type(8))) short bf16x8;
typedef __attribute__((ext_vector_type(4))) float f32x4;

__device__ __forceinline__ unsigned short f2bf(float f) {
    __hip_bfloat16 h = __float2bfloat16(f);
    return *(unsigned short*)&h;
}
__device__ __forceinline__ float bf2f(unsigned short u) {
    return __uint_as_float(((unsigned)u) << 16);
}

// ---------- helpers ----------
__device__ __forceinline__ unsigned sortable32(float f) {
    unsigned u = __float_as_uint(f);
    return u ^ ((unsigned)((int)u >> 31) | 0x80000000u);
}

__device__ __forceinline__ void cas_asc(unsigned long long &a, unsigned long long &b) {
    unsigned long long lo = a < b ? a : b;
    unsigned long long hi = a < b ? b : a;
    a = lo; b = hi;
}

__device__ __forceinline__ void sort16u(unsigned long long k[16]) {
    #pragma unroll
    for (int kk = 2; kk <= 16; kk <<= 1) {
        #pragma unroll
        for (int j = kk >> 1; j > 0; j >>= 1) {
            #pragma unroll
            for (int i = 0; i < 16; ++i) {
                const int l = i ^ j;
                if (l > i) {
                    if ((i & kk) == 0) cas_asc(k[i], k[l]);
                    else               cas_asc(k[l], k[i]);
                }
            }
        }
    }
}

__device__ __forceinline__ void clean16u(unsigned long long k[16]) {
    #pragma unroll
    for (int j = 8; j > 0; j >>= 1) {
        #pragma unroll
        for (int i = 0; i < 16; ++i) {
            const int l = i ^ j;
            if (l > i) cas_asc(k[i], k[l]);
        }
    }
}

// ---------- KNN + covariance (+ folded w_gl2 conversion blocks) ----------
__global__ __launch_bounds__(256)
void knn_cov_kernel(const float* __restrict__ x, const int* __restrict__ mask,
                    int* __restrict__ idx_out, float* __restrict__ h0,
                    const float* __restrict__ w_gl2,
                    unsigned short* __restrict__ wTh, unsigned short* __restrict__ wTl)
{
    const int tid = threadIdx.x;
    if (blockIdx.x >= 4096) {
        const int t = (blockIdx.x - 4096) * 256 + tid;   // t = n*128 + k
        const int n = t >> 7, k = t & 127;
        const float v = w_gl2[(size_t)k * 1024 + n];
        const unsigned short hi = f2bf(v);
        wTh[t] = hi;
        wTl[t] = f2bf(v - bf2f(hi));
        return;
    }

    __shared__ float4 cand[NPTS];
    const int wave = tid >> 6;
    const int lane = tid & 63;
    const int b = blockIdx.x >> 9;
    const int q = ((blockIdx.x & 511) << 2) + wave;
    const float* xb = x + (size_t)b * 3 * NPTS;
    const int*   mb = mask + b * NPTS;

    for (int m = tid; m < NPTS; m += 256) {
        float px = xb[m], py = xb[NPTS + m], pz = xb[2 * NPTS + m];
        float sq = px * px + py * py + pz * pz;
        if (mb[m] != 1) sq = INFINITY;
        cand[m] = make_float4(px, py, pz, sq);
    }
    __syncthreads();

    const float4 qc = cand[q];
    const float qx = qc.x, qy = qc.y, qz = qc.z;
    const float sqn = qx * qx + qy * qy + qz * qz;

    unsigned long long ld[16];
    #pragma unroll
    for (int t = 0; t < 16; ++t) {
        const int m = t * 64 + lane;
        const float4 c = cand[m];
        const float d = fmaf(-2.f, qx * c.x + qy * c.y + qz * c.z, sqn + c.w);
        ld[t] = ((unsigned long long)sortable32(d) << 32) | (unsigned)m;
    }
    sort16u(ld);

    unsigned long long cb[16];
    #pragma unroll
    for (int t = 0; t < 16; ++t) {
        const int m = (16 + t) * 64 + lane;
        const float4 c = cand[m];
        const float d = fmaf(-2.f, qx * c.x + qy * c.y + qz * c.z, sqn + c.w);
        cb[t] = ((unsigned long long)sortable32(d) << 32) | (unsigned)m;
    }
    sort16u(cb);

    {
        unsigned long long mg[16];
        #pragma unroll
        for (int i = 0; i < 16; ++i) {
            const unsigned long long a = ld[i], b2 = cb[15 - i];
            mg[i] = a < b2 ? a : b2;
        }
        clean16u(mg);
        #pragma unroll
        for (int i = 0; i < 16; ++i) ld[i] = mg[i];
    }

    #pragma unroll
    for (int p = 1; p <= 32; p <<= 1) {
        unsigned long long c2[16];
        #pragma unroll
        for (int i = 0; i < 16; ++i) {
            const unsigned long long pr = __shfl_xor(ld[15 - i], p, 64);
            c2[i] = ld[i] < pr ? ld[i] : pr;
        }
        clean16u(c2);
        #pragma unroll
        for (int i = 0; i < 16; ++i) ld[i] = c2[i];
    }

    const int gq = b * NPTS + q;
    if (lane < KNN)
        idx_out[gq * KNN + lane] = b * NPTS + (int)(unsigned)ld[lane];

    const int ml = (int)(unsigned)ld[lane & 15];
    const float4 nb = cand[ml];
    float sx = nb.x, sy = nb.y, sz = nb.z;
    #pragma unroll
    for (int m = 1; m < 16; m <<= 1) {
        sx += __shfl_xor(sx, m, 64); sy += __shfl_xor(sy, m, 64); sz += __shfl_xor(sz, m, 64);
    }
    const float mx = sx * 0.0625f, my = sy * 0.0625f, mz = sz * 0.0625f;
    const float cx = nb.x - mx, cy = nb.y - my, cz = nb.z - mz;
    float xx = cx * cx, xy = cx * cy, xz = cx * cz;
    float yy = cy * cy, yz = cy * cz, zz = cz * cz;
    #pragma unroll
    for (int m = 1; m < 16; m <<= 1) {
        xx += __shfl_xor(xx, m, 64); xy += __shfl_xor(xy, m, 64); xz += __shfl_xor(xz, m, 64);
        yy += __shfl_xor(yy, m, 64); yz += __shfl_xor(yz, m, 64); zz += __shfl_xor(zz, m, 64);
    }
    if (lane == 0) {
        float* o = h0 + (size_t)gq * 12;
        o[0] = qx; o[1] = qy; o[2] = qz;
        o[3] = xx; o[4] = xy; o[5] = xz;
        o[6] = xy; o[7] = yy; o[8] = yz;
        o[9] = xz; o[10] = yz; o[11] = zz;
    }
}

// ---------- broadcast GEMM for skinny K (K<=64, C in {64,128}) ----------
// Lane owns one output column (W column in regs); X row broadcast via readlane.
// Stats chunks written CHANNEL-MAJOR: ops[c*1024 + chunk].
template<int K, int C>
__global__ __launch_bounds__(256)
void bgemm_kernel(const float* __restrict__ X, const float* __restrict__ W,
                  const float* __restrict__ bias,
                  const float* __restrict__ xsc, const float* __restrict__ xsh,
                  float* __restrict__ Y, float* __restrict__ ops, float* __restrict__ opss)
{
    constexpr int NWC = C / 64;
    constexpr int NWR = 4 / NWC;
    constexpr int RPB = 16;
    constexpr int RPW = RPB / NWR;
    const int tid = threadIdx.x, wave = tid >> 6, lane = tid & 63;
    const int wr = wave / NWC, wc = wave % NWC;
    const int col = wc * 64 + lane;

    float wreg[K];
    #pragma unroll
    for (int k = 0; k < K; ++k) wreg[k] = W[(size_t)k * C + col];
    const float bv = bias[col];

    const bool bnx = (xsc != nullptr);
    float ksc = 0.f, ksh = 0.f;
    if (bnx && lane < K) { ksc = xsc[lane]; ksh = xsh[lane]; }

    float s = 0.f, ss = 0.f;
    const int row0 = blockIdx.x * RPB + wr * RPW;
    for (int r = 0; r < RPW; ++r) {
        const int row = row0 + r;
        float xv = (lane < K) ? X[(size_t)row * K + lane] : 0.f;
        if (bnx) xv = fmaxf(0.f, fmaf(xv, ksc, ksh));
        float acc = 0.f;
        #pragma unroll
        for (int k = 0; k < K; ++k) {
            const float xk = __uint_as_float(
                (unsigned)__builtin_amdgcn_readlane((int)__float_as_uint(xv), k));
            acc = fmaf(xk, wreg[k], acc);
        }
        const float yv = acc + bv;
        Y[(size_t)row * C + col] = yv;
        s += yv; ss = fmaf(yv, yv, ss);
    }

    __shared__ float red[4][64], red2[4][64];
    red[wave][lane] = s; red2[wave][lane] = ss;
    __syncthreads();
    if (tid < C) {
        float S = 0.f, SS = 0.f;
        #pragma unroll
        for (int w2 = 0; w2 < NWR; ++w2) {
            const int widx = w2 * NWC + (tid >> 6);
            S += red[widx][tid & 63]; SS += red2[widx][tid & 63];
        }
        ops[(size_t)tid * 1024 + blockIdx.x] = S;
        opss[(size_t)tid * 1024 + blockIdx.x] = SS;
    }
}

// ---------- stats finalize (channel-major chunks): wave per channel ----------
// grid = C/4 blocks x 256 threads. NCH = chunks per channel (contiguous).
template<int C, int NCH>
__global__ void stats_final_t(const float* __restrict__ ps, const float* __restrict__ pss,
                              const float* __restrict__ g, const float* __restrict__ be,
                              float* __restrict__ sc, float* __restrict__ sh,
                              float* __restrict__ pooled)
{
    const int wave = threadIdx.x >> 6, lane = threadIdx.x & 63;
    const int ch = (blockIdx.x << 2) + wave;
    if (pooled && threadIdx.x < 32) pooled[blockIdx.x * 32 + threadIdx.x] = 0.f;
    constexpr int IT = NCH / 64;
    float s = 0.f, ss = 0.f;
    #pragma unroll
    for (int j = 0; j < IT; ++j) {
        s  += ps[(size_t)ch * NCH + j * 64 + lane];
        ss += pss[(size_t)ch * NCH + j * 64 + lane];
    }
    #pragma unroll
    for (int off = 32; off > 0; off >>= 1) {
        s += __shfl_xor(s, off, 64);
        ss += __shfl_xor(ss, off, 64);
    }
    if (lane == 0) {
        const float invM = 1.f / (float)MROWS;
        const float mean = s * invM;
        const float var = fmaxf(ss * invM - mean * mean, 0.f);
        const float scv = g[ch] * rsqrtf(var + 1e-5f);
        sc[ch] = scv;
        sh[ch] = be[ch] - mean * scv;
    }
}

// ---------- gl2 MFMA GEMM (split-bf16, 3 passes) + channel-major psum chunks ----------
__global__ __launch_bounds__(256)
void gemm_gl2_mfma(const unsigned short* __restrict__ Ahi, const unsigned short* __restrict__ Alo,
                   const unsigned short* __restrict__ Whi, const unsigned short* __restrict__ Wlo,
                   const float* __restrict__ bias, float* __restrict__ Y,
                   float* __restrict__ ops, float* __restrict__ opss)
{
    __shared__ float ps[2][128], pss2[2][128];
    const int wave = threadIdx.x >> 6, lane = threadIdx.x & 63;
    const int wm = wave >> 1, wn = wave & 1;
    const int bm = blockIdx.x * 128 + wm * 64;
    const int bn = blockIdx.y * 128 + wn * 64;
    const int lrow = lane & 15;
    const int lk = (lane >> 4) * 8;
    f32x4 acc[4][4] = {};
    #pragma unroll
    for (int ks = 0; ks < 4; ++ks) {
        const int k0 = ks * 32 + lk;
        bf16x8 ah[4], al[4], bh[4], bl[4];
        #pragma unroll
        for (int mf = 0; mf < 4; ++mf) {
            const size_t off = (size_t)(bm + mf * 16 + lrow) * 128 + k0;
            ah[mf] = *(const bf16x8*)(Ahi + off);
            al[mf] = *(const bf16x8*)(Alo + off);
        }
        #pragma unroll
        for (int nf = 0; nf < 4; ++nf) {
            const size_t off = (size_t)(bn + nf * 16 + lrow) * 128 + k0;
            bh[nf] = *(const bf16x8*)(Whi + off);
            bl[nf] = *(const bf16x8*)(Wlo + off);
        }
        #pragma unroll
        for (int mf = 0; mf < 4; ++mf)
            #pragma unroll
            for (int nf = 0; nf < 4; ++nf) {
                acc[mf][nf] = __builtin_amdgcn_mfma_f32_16x16x32_bf16(ah[mf], bh[nf], acc[mf][nf], 0, 0, 0);
                acc[mf][nf] = __builtin_amdgcn_mfma_f32_16x16x32_bf16(ah[mf], bl[nf], acc[mf][nf], 0, 0, 0);
                acc[mf][nf] = __builtin_amdgcn_mfma_f32_16x16x32_bf16(al[mf], bh[nf], acc[mf][nf], 0, 0, 0);
            }
    }
    const int r0 = (lane >> 4) * 4, cc = lane & 15;
    float s[4] = {0.f, 0.f, 0.f, 0.f}, sq2[4] = {0.f, 0.f, 0.f, 0.f};
    #pragma unroll
    for (int mf = 0; mf < 4; ++mf) {
        const int row = bm + mf * 16 + r0;
        #pragma unroll
        for (int nf = 0; nf < 4; ++nf) {
            const int col = bn + nf * 16 + cc;
            const float bv = bias[col];
            #pragma unroll
            for (int r = 0; r < 4; ++r) {
                const float yv = acc[mf][nf][r] + bv;
                Y[(size_t)(row + r) * 1024 + col] = yv;
                s[nf] += yv; sq2[nf] = fmaf(yv, yv, sq2[nf]);
            }
        }
    }
    #pragma unroll
    for (int nf = 0; nf < 4; ++nf) {
        #pragma unroll
        for (int off = 16; off < 64; off <<= 1) {
            s[nf]   += __shfl_xor(s[nf], off, 64);
            sq2[nf] += __shfl_xor(sq2[nf], off, 64);
        }
    }
    if (lane < 16) {
        #pragma unroll
        for (int nf = 0; nf < 4; ++nf) {
            ps[wm][wn * 64 + nf * 16 + lane] = s[nf];
            pss2[wm][wn * 64 + nf * 16 + lane] = sq2[nf];
        }
    }
    __syncthreads();
    if (threadIdx.x < 128) {
        const int ch = blockIdx.y * 128 + threadIdx.x;
        ops[(size_t)ch * 128 + blockIdx.x]  = ps[0][threadIdx.x] + ps[1][threadIdx.x];
        opss[(size_t)ch * 128 + blockIdx.x] = pss2[0][threadIdx.x] + pss2[1][threadIdx.x];
    }
}

// ---------- gather-max + BN(direct), 64 ch ----------
__global__ __launch_bounds__(256)
void gathermax_bn64(const float* __restrict__ Hin, const int* __restrict__ idxmat,
                    const float* __restrict__ scv, const float* __restrict__ shv,
                    float* __restrict__ Z)
{
    const int c4 = threadIdx.x & 15, rr = threadIdx.x >> 4;
    const int row = (blockIdx.x << 4) + rr;
    const int* ip = idxmat + (size_t)row * KNN;
    const float4 sc = ((const float4*)scv)[c4], sh = ((const float4*)shv)[c4];
    float4 m = {0.f, 0.f, 0.f, 0.f};
    #pragma unroll
    for (int k = 0; k < KNN; ++k) {
        const int j = ip[k];
        const float4 v = *(const float4*)(Hin + (size_t)j * 64 + c4 * 4);
        m.x = fmaxf(m.x, fmaf(v.x, sc.x, sh.x));
        m.y = fmaxf(m.y, fmaf(v.y, sc.y, sh.y));
        m.z = fmaxf(m.z, fmaf(v.z, sc.z, sh.z));
        m.w = fmaxf(m.w, fmaf(v.w, sc.w, sh.w));
    }
    ((float4*)(Z + (size_t)row * 64))[c4] = m;
}

// ---------- gather-max + BN(direct), 128 ch, split-bf16 out ----------
__global__ __launch_bounds__(256)
void gathermax_bn128_split(const float* __restrict__ Hin, const int* __restrict__ idxmat,
                           const float* __restrict__ scv, const float* __restrict__ shv,
                           unsigned short* __restrict__ Zhi, unsigned short* __restrict__ Zlo)
{
    const int c4 = threadIdx.x & 31, rr = threadIdx.x >> 5;
    const int row = (blockIdx.x << 3) + rr;
    const int* ip = idxmat + (size_t)row * KNN;
    const float4 sc = ((const float4*)scv)[c4], sh = ((const float4*)shv)[c4];
    float4 m = {0.f, 0.f, 0.f, 0.f};
    #pragma unroll
    for (int k = 0; k < KNN; ++k) {
        const int j = ip[k];
        const float4 v = *(const float4*)(Hin + (size_t)j * 128 + c4 * 4);
        m.x = fmaxf(m.x, fmaf(v.x, sc.x, sh.x));
        m.y = fmaxf(m.y, fmaf(v.y, sc.y, sh.y));
        m.z = fmaxf(m.z, fmaf(v.z, sc.z, sh.z));
        m.w = fmaxf(m.w, fmaf(v.w, sc.w, sh.w));
    }
    ushort4 hi, lo;
    hi.x = f2bf(m.x); lo.x = f2bf(m.x - bf2f(hi.x));
    hi.y = f2bf(m.y); lo.y = f2bf(m.y - bf2f(hi.y));
    hi.z = f2bf(m.z); lo.z = f2bf(m.z - bf2f(hi.z));
    hi.w = f2bf(m.w); lo.w = f2bf(m.w - bf2f(hi.w));
    *(ushort4*)(Zhi + (size_t)row * 128 + c4 * 4) = hi;
    *(ushort4*)(Zlo + (size_t)row * 128 + c4 * 4) = lo;
}

// ---------- fused bnrelu + masked segment max, fp32 ----------
__global__ __launch_bounds__(256)
void segmax_bnrelu_f32(const float* __restrict__ Y, const float* __restrict__ scale,
                       const float* __restrict__ shift, const int* __restrict__ mask,
                       unsigned* __restrict__ pooled)
{
    __shared__ int mk[64];
    const int b = blockIdx.x, nc = blockIdx.y;
    const int n0 = nc * 64;
    if (threadIdx.x < 64) mk[threadIdx.x] = mask[b * NPTS + n0 + threadIdx.x];
    __syncthreads();
    const int c4 = threadIdx.x;
    const float4 sc = ((const float4*)scale)[c4], sh = ((const float4*)shift)[c4];
    float4 m = {0.f, 0.f, 0.f, 0.f};
    for (int n = 0; n < 64; ++n) {
        if (mk[n]) {
            const float4 v = ((const float4*)(Y + ((size_t)b * NPTS + n0 + n) * 1024))[c4];
            m.x = fmaxf(m.x, fmaf(v.x, sc.x, sh.x));
            m.y = fmaxf(m.y, fmaf(v.y, sc.y, sh.y));
            m.z = fmaxf(m.z, fmaf(v.z, sc.z, sh.z));
            m.w = fmaxf(m.w, fmaf(v.w, sc.w, sh.w));
        }
    }
    m.x = fmaxf(m.x, 0.f); m.y = fmaxf(m.y, 0.f); m.z = fmaxf(m.z, 0.f); m.w = fmaxf(m.w, 0.f);
    atomicMax(&pooled[b * 1024 + c4 * 4 + 0], __float_as_uint(m.x));
    atomicMax(&pooled[b * 1024 + c4 * 4 + 1], __float_as_uint(m.y));
    atomicMax(&pooled[b * 1024 + c4 * 4 + 2], __float_as_uint(m.z));
    atomicMax(&pooled[b * 1024 + c4 * 4 + 3], __float_as_uint(m.w));
}

// ---------- head: 8-row GEMM + BN(8) + ReLU; 64 blocks x 8 cols, 32-way K-split ----------
template<int KDIM>
__global__ __launch_bounds__(256)
void mlp8_kernel(const float* __restrict__ In, const float* __restrict__ W,
                 const float* __restrict__ bias, const float* __restrict__ g,
                 const float* __restrict__ be, float* __restrict__ Out)
{
    __shared__ float Ins[8 * KDIM];
    __shared__ float part[32][8][8];
    __shared__ float ys[8][8];
    const int tid = threadIdx.x;
    for (int e = tid; e < 8 * KDIM; e += 256) Ins[e] = In[e];
    __syncthreads();
    const int c = tid & 7, kp = tid >> 3;
    const int col = (blockIdx.x << 3) + c;
    constexpr int KS = KDIM / 32;
    float a[8] = {};
    for (int k = kp * KS; k < (kp + 1) * KS; ++k) {
        const float w = W[(size_t)k * 512 + col];
        #pragma unroll
        for (int r = 0; r < 8; ++r) a[r] = fmaf(Ins[r * KDIM + k], w, a[r]);
    }
    #pragma unroll
    for (int r = 0; r < 8; ++r) part[kp][r][c] = a[r];
    __syncthreads();
    if (tid < 64) {
        const int r = tid >> 3, cc = tid & 7;
        float s = 0.f;
        #pragma unroll
        for (int p = 0; p < 32; ++p) s += part[p][r][cc];
        ys[r][cc] = s + bias[(blockIdx.x << 3) + cc];
    }
    __syncthreads();
    if (tid < 8) {
        const int c2 = (blockIdx.x << 3) + tid;
        float s = 0.f, ss = 0.f;
        #pragma unroll
        for (int r = 0; r < 8; ++r) { const float v = ys[r][tid]; s += v; ss = fmaf(v, v, ss); }
        const float mean = s * 0.125f;
        const float var = fmaxf(ss * 0.125f - mean * mean, 0.f);
        const float sc = g[c2] * rsqrtf(var + 1e-5f);
        const float sh = be[c2] - mean * sc;
        #pragma unroll
        for (int r = 0; r < 8; ++r)
            Out[r * 512 + c2] = fmaxf(0.f, fmaf(ys[r][tid], sc, sh));
    }
}

// ---------- launcher ----------
extern "C" void kernel_launch(void* const* d_in, const int* in_sizes, int n_in,
                              void* d_out, int out_size, void* d_ws, size_t ws_size,
                              hipStream_t stream)
{
    const float* x    = (const float*)d_in[0];
    const int*   mask = (const int*)d_in[1];
    const float* w_m1a = (const float*)d_in[2];
    const float* b_m1a = (const float*)d_in[3];
    const float* g_m1a = (const float*)d_in[4];
    const float* be_m1a = (const float*)d_in[5];
    const float* w_m1b = (const float*)d_in[6];
    const float* b_m1b = (const float*)d_in[7];
    const float* g_m1b = (const float*)d_in[8];
    const float* be_m1b = (const float*)d_in[9];
    const float* w_m1c = (const float*)d_in[10];
    const float* b_m1c = (const float*)d_in[11];
    const float* g_m1c = (const float*)d_in[12];
    const float* be_m1c = (const float*)d_in[13];
    const float* w_gl1 = (const float*)d_in[14];
    const float* b_gl1 = (const float*)d_in[15];
    const float* g_gl1 = (const float*)d_in[16];
    const float* be_gl1 = (const float*)d_in[17];
    const float* w_gl2 = (const float*)d_in[18];
    const float* b_gl2 = (const float*)d_in[19];
    const float* g_gl2 = (const float*)d_in[20];
    const float* be_gl2 = (const float*)d_in[21];
    const float* w_m2a = (const float*)d_in[22];
    const float* b_m2a = (const float*)d_in[23];
    const float* g_m2a = (const float*)d_in[24];
    const float* be_m2a = (const float*)d_in[25];
    const float* w_m2b = (const float*)d_in[26];
    const float* b_m2b = (const float*)d_in[27];
    const float* g_m2b = (const float*)d_in[28];
    const float* be_m2b = (const float*)d_in[29];

    float* ws = (float*)d_ws;
    int*   idx  = (int*)ws;                              // +262144
    float* h0   = ws + 262144;                           // +196608
    float* bufA = ws + 458752;                           // +1048576
    float* bufB = ws + 1507328;                          // +1048576
    float* bufC = ws + 2555904;                          // +2097152
    unsigned short* wTh = (unsigned short*)(ws + 4653056);   // +65536
    unsigned short* wTl = (unsigned short*)(ws + 4718592);   // +65536
    float* bufE  = ws + 4784128;                         // +16777216
    float* pooled = ws + 21561344;                       // +8192
    float* y1     = ws + 21569536;                       // +4096
    float* ps0    = ws + 21573632;                       // +131072
    float* pss0   = ws + 21704704;                       // +131072
    float* ps1    = ws + 21835776;                       // +131072
    float* pss1   = ws + 21966848;                       // +131072
    float* scale  = ws + 22097920;                       // +1024
    float* shift  = ws + 22098944;                       // +1024

    unsigned short* Ahi = (unsigned short*)bufA;
    unsigned short* Alo = (unsigned short*)bufB;

    // knn + folded w_gl2 conversion
    knn_cov_kernel<<<4608, 256, 0, stream>>>(x, mask, idx, h0, w_gl2, wTh, wTl);

    // m1a: 12 -> 64
    bgemm_kernel<12, 64><<<1024, 256, 0, stream>>>(
        h0, w_m1a, b_m1a, nullptr, nullptr, bufA, ps0, pss0);
    stats_final_t<64, 1024><<<16, 256, 0, stream>>>(ps0, pss0, g_m1a, be_m1a, scale, shift, nullptr);

    // m1b: 64 -> 64 (bn_m1a folded at X load)
    bgemm_kernel<64, 64><<<1024, 256, 0, stream>>>(
        bufA, w_m1b, b_m1b, scale, shift, bufB, ps1, pss1);
    stats_final_t<64, 1024><<<16, 256, 0, stream>>>(ps1, pss1, g_m1b, be_m1b, scale, shift, nullptr);

    // m1c: 64 -> 64 (bn_m1b folded)
    bgemm_kernel<64, 64><<<1024, 256, 0, stream>>>(
        bufB, w_m1c, b_m1c, scale, shift, bufA, ps0, pss0);
    stats_final_t<64, 1024><<<16, 256, 0, stream>>>(ps0, pss0, g_m1c, be_m1c, scale, shift, nullptr);

    // gather-max 64 (bn_m1c direct)
    gathermax_bn64<<<1024, 256, 0, stream>>>(bufA, idx, scale, shift, bufB);

    // gl1: 64 -> 128
    bgemm_kernel<64, 128><<<1024, 256, 0, stream>>>(
        bufB, w_gl1, b_gl1, nullptr, nullptr, bufC, ps1, pss1);
    stats_final_t<128, 1024><<<32, 256, 0, stream>>>(ps1, pss1, g_gl1, be_gl1, scale, shift, nullptr);

    // gather-max 128 (bn_gl1 direct) -> split-bf16 A
    gathermax_bn128_split<<<2048, 256, 0, stream>>>(bufC, idx, scale, shift, Ahi, Alo);

    // gl2: 128 -> 1024, split-bf16 MFMA + channel-major stats chunks
    gemm_gl2_mfma<<<dim3(128, 8), 256, 0, stream>>>(Ahi, Alo, wTh, wTl, b_gl2, bufE, ps0, pss0);
    stats_final_t<1024, 128><<<256, 256, 0, stream>>>(ps0, pss0, g_gl2, be_gl2, scale, shift, pooled);

    // fused bnrelu + masked segment-max
    segmax_bnrelu_f32<<<dim3(8, 32), 256, 0, stream>>>(bufE, scale, shift, mask, (unsigned*)pooled);

    // head
    mlp8_kernel<1024><<<64, 256, 0, stream>>>(pooled, w_m2a, b_m2a, g_m2a, be_m2a, y1);
    mlp8_kernel<512><<<64, 256, 0, stream>>>(y1, w_m2b, b_m2b, g_m2b, be_m2b, (float*)d_out);
}

// Round 11
// 210.872 us; speedup vs baseline: 2.9078x; 1.1171x over previous
//
#include <hip/hip_runtime.h>
#include <hip/hip_bf16.h>
#include <stdint.h>
#include <math.h>

#define NPTS 2048
#define BSZ 8
#define KNN 16
#define MROWS (BSZ * NPTS)   // 16384

typedef __attribute__((ext_vector_type(8))) short bf16x8;
typedef __attribute__((ext_vector_type(4))) float f32x4;

__device__ __forceinline__ unsigned short f2bf(float f) {
    __hip_bfloat16 h = __float2bfloat16(f);
    return *(unsigned short*)&h;
}
__device__ __forceinline__ float bf2f(unsigned short u) {
    return __uint_as_float(((unsigned)u) << 16);
}

// ---------- helpers ----------
__device__ __forceinline__ unsigned sortable32(float f) {
    unsigned u = __float_as_uint(f);
    return u ^ ((unsigned)((int)u >> 31) | 0x80000000u);
}
__device__ __forceinline__ float unsortable32(unsigned s) {
    return __uint_as_float((s & 0x80000000u) ? (s ^ 0x80000000u) : ~s);
}

__device__ __forceinline__ void cas_asc(unsigned long long &a, unsigned long long &b) {
    unsigned long long lo = a < b ? a : b;
    unsigned long long hi = a < b ? b : a;
    a = lo; b = hi;
}

__device__ __forceinline__ void sort16u(unsigned long long k[16]) {
    #pragma unroll
    for (int kk = 2; kk <= 16; kk <<= 1) {
        #pragma unroll
        for (int j = kk >> 1; j > 0; j >>= 1) {
            #pragma unroll
            for (int i = 0; i < 16; ++i) {
                const int l = i ^ j;
                if (l > i) {
                    if ((i & kk) == 0) cas_asc(k[i], k[l]);
                    else               cas_asc(k[l], k[i]);
                }
            }
        }
    }
}

__device__ __forceinline__ void clean16u(unsigned long long k[16]) {
    #pragma unroll
    for (int j = 8; j > 0; j >>= 1) {
        #pragma unroll
        for (int i = 0; i < 16; ++i) {
            const int l = i ^ j;
            if (l > i) cas_asc(k[i], k[l]);
        }
    }
}

// ---------- KNN + covariance, 512 threads (8 queries/block) ----------
// blocks [0,2048): knn. blocks [2048,2304): w_gl2 split-bf16 conversion.
__global__ __launch_bounds__(512)
void knn_cov_kernel(const float* __restrict__ x, const int* __restrict__ mask,
                    int* __restrict__ idx_out, float* __restrict__ h0,
                    const float* __restrict__ w_gl2,
                    unsigned short* __restrict__ wTh, unsigned short* __restrict__ wTl)
{
    const int tid = threadIdx.x;
    if (blockIdx.x >= 2048) {
        const int t = (blockIdx.x - 2048) * 512 + tid;   // t = n*128 + k
        const int n = t >> 7, k = t & 127;
        const float v = w_gl2[(size_t)k * 1024 + n];
        const unsigned short hi = f2bf(v);
        wTh[t] = hi;
        wTl[t] = f2bf(v - bf2f(hi));
        return;
    }

    __shared__ float4 cand[NPTS];
    const int wave = tid >> 6;
    const int lane = tid & 63;
    const int b = blockIdx.x >> 8;                    // 256 blocks per batch
    const int q = ((blockIdx.x & 255) << 3) + wave;
    const float* xb = x + (size_t)b * 3 * NPTS;
    const int*   mb = mask + b * NPTS;

    for (int m = tid; m < NPTS; m += 512) {
        float px = xb[m], py = xb[NPTS + m], pz = xb[2 * NPTS + m];
        float sq = px * px + py * py + pz * pz;
        if (mb[m] != 1) sq = INFINITY;
        cand[m] = make_float4(px, py, pz, sq);
    }
    __syncthreads();

    const float4 qc = cand[q];
    const float qx = qc.x, qy = qc.y, qz = qc.z;
    const float sqn = qx * qx + qy * qy + qz * qz;

    unsigned long long ld[16];
    #pragma unroll
    for (int t = 0; t < 16; ++t) {
        const int m = t * 64 + lane;
        const float4 c = cand[m];
        const float d = fmaf(-2.f, qx * c.x + qy * c.y + qz * c.z, sqn + c.w);
        ld[t] = ((unsigned long long)sortable32(d) << 32) | (unsigned)m;
    }
    sort16u(ld);

    unsigned long long cb[16];
    #pragma unroll
    for (int t = 0; t < 16; ++t) {
        const int m = (16 + t) * 64 + lane;
        const float4 c = cand[m];
        const float d = fmaf(-2.f, qx * c.x + qy * c.y + qz * c.z, sqn + c.w);
        cb[t] = ((unsigned long long)sortable32(d) << 32) | (unsigned)m;
    }
    sort16u(cb);

    {
        unsigned long long mg[16];
        #pragma unroll
        for (int i = 0; i < 16; ++i) {
            const unsigned long long a = ld[i], b2 = cb[15 - i];
            mg[i] = a < b2 ? a : b2;
        }
        clean16u(mg);
        #pragma unroll
        for (int i = 0; i < 16; ++i) ld[i] = mg[i];
    }

    #pragma unroll
    for (int p = 1; p <= 32; p <<= 1) {
        unsigned long long c2[16];
        #pragma unroll
        for (int i = 0; i < 16; ++i) {
            const unsigned long long pr = __shfl_xor(ld[15 - i], p, 64);
            c2[i] = ld[i] < pr ? ld[i] : pr;
        }
        clean16u(c2);
        #pragma unroll
        for (int i = 0; i < 16; ++i) ld[i] = c2[i];
    }

    const int gq = b * NPTS + q;
    if (lane < KNN)
        idx_out[gq * KNN + lane] = b * NPTS + (int)(unsigned)ld[lane];

    const int ml = (int)(unsigned)ld[lane & 15];
    const float4 nb = cand[ml];
    float sx = nb.x, sy = nb.y, sz = nb.z;
    #pragma unroll
    for (int m = 1; m < 16; m <<= 1) {
        sx += __shfl_xor(sx, m, 64); sy += __shfl_xor(sy, m, 64); sz += __shfl_xor(sz, m, 64);
    }
    const float mx = sx * 0.0625f, my = sy * 0.0625f, mz = sz * 0.0625f;
    const float cx = nb.x - mx, cy = nb.y - my, cz = nb.z - mz;
    float xx = cx * cx, xy = cx * cy, xz = cx * cz;
    float yy = cy * cy, yz = cy * cz, zz = cz * cz;
    #pragma unroll
    for (int m = 1; m < 16; m <<= 1) {
        xx += __shfl_xor(xx, m, 64); xy += __shfl_xor(xy, m, 64); xz += __shfl_xor(xz, m, 64);
        yy += __shfl_xor(yy, m, 64); yz += __shfl_xor(yz, m, 64); zz += __shfl_xor(zz, m, 64);
    }
    if (lane == 0) {
        float* o = h0 + (size_t)gq * 12;
        o[0] = qx; o[1] = qy; o[2] = qz;
        o[3] = xx; o[4] = xy; o[5] = xz;
        o[6] = xy; o[7] = yy; o[8] = yz;
        o[9] = xz; o[10] = yz; o[11] = zz;
    }
}

// ---------- broadcast GEMM for skinny K; channel-major stats chunks ----------
template<int K, int C>
__global__ __launch_bounds__(256)
void bgemm_kernel(const float* __restrict__ X, const float* __restrict__ W,
                  const float* __restrict__ bias,
                  const float* __restrict__ xsc, const float* __restrict__ xsh,
                  float* __restrict__ Y, float* __restrict__ ops, float* __restrict__ opss)
{
    constexpr int NWC = C / 64;
    constexpr int NWR = 4 / NWC;
    constexpr int RPB = 16;
    constexpr int RPW = RPB / NWR;
    const int tid = threadIdx.x, wave = tid >> 6, lane = tid & 63;
    const int wr = wave / NWC, wc = wave % NWC;
    const int col = wc * 64 + lane;

    float wreg[K];
    #pragma unroll
    for (int k = 0; k < K; ++k) wreg[k] = W[(size_t)k * C + col];
    const float bv = bias[col];

    const bool bnx = (xsc != nullptr);
    float ksc = 0.f, ksh = 0.f;
    if (bnx && lane < K) { ksc = xsc[lane]; ksh = xsh[lane]; }

    float s = 0.f, ss = 0.f;
    const int row0 = blockIdx.x * RPB + wr * RPW;
    for (int r = 0; r < RPW; ++r) {
        const int row = row0 + r;
        float xv = (lane < K) ? X[(size_t)row * K + lane] : 0.f;
        if (bnx) xv = fmaxf(0.f, fmaf(xv, ksc, ksh));
        float acc = 0.f;
        #pragma unroll
        for (int k = 0; k < K; ++k) {
            const float xk = __uint_as_float(
                (unsigned)__builtin_amdgcn_readlane((int)__float_as_uint(xv), k));
            acc = fmaf(xk, wreg[k], acc);
        }
        const float yv = acc + bv;
        Y[(size_t)row * C + col] = yv;
        s += yv; ss = fmaf(yv, yv, ss);
    }

    __shared__ float red[4][64], red2[4][64];
    red[wave][lane] = s; red2[wave][lane] = ss;
    __syncthreads();
    if (tid < C) {
        float S = 0.f, SS = 0.f;
        #pragma unroll
        for (int w2 = 0; w2 < NWR; ++w2) {
            const int widx = w2 * NWC + (tid >> 6);
            S += red[widx][tid & 63]; SS += red2[widx][tid & 63];
        }
        ops[(size_t)tid * 1024 + blockIdx.x] = S;
        opss[(size_t)tid * 1024 + blockIdx.x] = SS;
    }
}

// ---------- stats finalize (channel-major chunks): wave per channel ----------
template<int C, int NCH>
__global__ void stats_final_t(const float* __restrict__ ps, const float* __restrict__ pss,
                              const float* __restrict__ g, const float* __restrict__ be,
                              float* __restrict__ sc, float* __restrict__ sh)
{
    const int wave = threadIdx.x >> 6, lane = threadIdx.x & 63;
    const int ch = (blockIdx.x << 2) + wave;
    constexpr int IT = NCH / 64;
    float s = 0.f, ss = 0.f;
    #pragma unroll
    for (int j = 0; j < IT; ++j) {
        s  += ps[(size_t)ch * NCH + j * 64 + lane];
        ss += pss[(size_t)ch * NCH + j * 64 + lane];
    }
    #pragma unroll
    for (int off = 32; off > 0; off >>= 1) {
        s += __shfl_xor(s, off, 64);
        ss += __shfl_xor(ss, off, 64);
    }
    if (lane == 0) {
        const float invM = 1.f / (float)MROWS;
        const float mean = s * invM;
        const float var = fmaxf(ss * invM - mean * mean, 0.f);
        const float scv = g[ch] * rsqrtf(var + 1e-5f);
        sc[ch] = scv;
        sh[ch] = be[ch] - mean * scv;
    }
}

// ---------- gl2 stats + pooled finalize: bn scale/shift, decode rawmax -> pooled ----------
// grid 256 x 256: wave per channel (1024 ch), 128 chunks each.
__global__ void stats_pool_final(const float* __restrict__ ps, const float* __restrict__ pss,
                                 const float* __restrict__ g, const float* __restrict__ be,
                                 const unsigned* __restrict__ rawmax, float* __restrict__ pooled)
{
    const int wave = threadIdx.x >> 6, lane = threadIdx.x & 63;
    const int ch = (blockIdx.x << 2) + wave;
    float s  = ps[(size_t)ch * 128 + lane] + ps[(size_t)ch * 128 + 64 + lane];
    float ss = pss[(size_t)ch * 128 + lane] + pss[(size_t)ch * 128 + 64 + lane];
    #pragma unroll
    for (int off = 32; off > 0; off >>= 1) {
        s += __shfl_xor(s, off, 64);
        ss += __shfl_xor(ss, off, 64);
    }
    const float invM = 1.f / (float)MROWS;
    const float mean = s * invM;
    const float var = fmaxf(ss * invM - mean * mean, 0.f);
    const float scv = g[ch] * rsqrtf(var + 1e-5f);
    const float shv = be[ch] - mean * scv;
    if (lane < 8) {
        const float v = unsortable32(rawmax[lane * 1024 + ch]);
        pooled[lane * 1024 + ch] = fmaxf(0.f, fmaf(v, scv, shv));
    }
}

// ---------- gl2 MFMA GEMM (split-bf16, 3 passes) + stats chunks + masked col-max ----------
// grid (128, 8). No Y materialization: masked per-column max -> atomicMax(rawmax).
__global__ __launch_bounds__(256)
void gemm_gl2_mfma(const unsigned short* __restrict__ Ahi, const unsigned short* __restrict__ Alo,
                   const unsigned short* __restrict__ Whi, const unsigned short* __restrict__ Wlo,
                   const float* __restrict__ bias, const int* __restrict__ mask,
                   unsigned* __restrict__ rawmax,
                   float* __restrict__ ops, float* __restrict__ opss)
{
    __shared__ float ps[2][128], pss2[2][128];
    __shared__ int mk[128];
    const int tid = threadIdx.x;
    if (tid < 128) mk[tid] = mask[blockIdx.x * 128 + tid];   // rows of this block
    __syncthreads();

    const int wave = tid >> 6, lane = tid & 63;
    const int wm = wave >> 1, wn = wave & 1;
    const int bm = blockIdx.x * 128 + wm * 64;
    const int bn = blockIdx.y * 128 + wn * 64;
    const int batch = blockIdx.x >> 4;                       // 16 blocks per batch
    const int lrow = lane & 15;
    const int lk = (lane >> 4) * 8;
    f32x4 acc[4][4] = {};
    #pragma unroll
    for (int ks = 0; ks < 4; ++ks) {
        const int k0 = ks * 32 + lk;
        bf16x8 ah[4], al[4], bh[4], bl[4];
        #pragma unroll
        for (int mf = 0; mf < 4; ++mf) {
            const size_t off = (size_t)(bm + mf * 16 + lrow) * 128 + k0;
            ah[mf] = *(const bf16x8*)(Ahi + off);
            al[mf] = *(const bf16x8*)(Alo + off);
        }
        #pragma unroll
        for (int nf = 0; nf < 4; ++nf) {
            const size_t off = (size_t)(bn + nf * 16 + lrow) * 128 + k0;
            bh[nf] = *(const bf16x8*)(Whi + off);
            bl[nf] = *(const bf16x8*)(Wlo + off);
        }
        #pragma unroll
        for (int mf = 0; mf < 4; ++mf)
            #pragma unroll
            for (int nf = 0; nf < 4; ++nf) {
                acc[mf][nf] = __builtin_amdgcn_mfma_f32_16x16x32_bf16(ah[mf], bh[nf], acc[mf][nf], 0, 0, 0);
                acc[mf][nf] = __builtin_amdgcn_mfma_f32_16x16x32_bf16(ah[mf], bl[nf], acc[mf][nf], 0, 0, 0);
                acc[mf][nf] = __builtin_amdgcn_mfma_f32_16x16x32_bf16(al[mf], bh[nf], acc[mf][nf], 0, 0, 0);
            }
    }
    const int r0 = (lane >> 4) * 4, cc = lane & 15;
    float s[4] = {0.f, 0.f, 0.f, 0.f}, sq2[4] = {0.f, 0.f, 0.f, 0.f};
    float cmax[4] = {-INFINITY, -INFINITY, -INFINITY, -INFINITY};
    #pragma unroll
    for (int mf = 0; mf < 4; ++mf) {
        const int blr = wm * 64 + mf * 16 + r0;              // block-local row base
        #pragma unroll
        for (int nf = 0; nf < 4; ++nf) {
            const int col = bn + nf * 16 + cc;
            const float bv = bias[col];
            #pragma unroll
            for (int r = 0; r < 4; ++r) {
                const float yv = acc[mf][nf][r] + bv;
                s[nf] += yv; sq2[nf] = fmaf(yv, yv, sq2[nf]);
                if (mk[blr + r]) cmax[nf] = fmaxf(cmax[nf], yv);
            }
        }
    }
    #pragma unroll
    for (int nf = 0; nf < 4; ++nf) {
        #pragma unroll
        for (int off = 16; off < 64; off <<= 1) {
            s[nf]   += __shfl_xor(s[nf], off, 64);
            sq2[nf] += __shfl_xor(sq2[nf], off, 64);
            cmax[nf] = fmaxf(cmax[nf], __shfl_xor(cmax[nf], off, 64));
        }
    }
    if (lane < 16) {
        #pragma unroll
        for (int nf = 0; nf < 4; ++nf) {
            ps[wm][wn * 64 + nf * 16 + lane] = s[nf];
            pss2[wm][wn * 64 + nf * 16 + lane] = sq2[nf];
            atomicMax(&rawmax[batch * 1024 + bn + nf * 16 + lane], sortable32(cmax[nf]));
        }
    }
    __syncthreads();
    if (tid < 128) {
        const int ch = blockIdx.y * 128 + tid;
        ops[(size_t)ch * 128 + blockIdx.x]  = ps[0][tid] + ps[1][tid];
        opss[(size_t)ch * 128 + blockIdx.x] = pss2[0][tid] + pss2[1][tid];
    }
}

// ---------- gather-max + BN(direct), 64 ch ----------
__global__ __launch_bounds__(256)
void gathermax_bn64(const float* __restrict__ Hin, const int* __restrict__ idxmat,
                    const float* __restrict__ scv, const float* __restrict__ shv,
                    float* __restrict__ Z)
{
    const int c4 = threadIdx.x & 15, rr = threadIdx.x >> 4;
    const int row = (blockIdx.x << 4) + rr;
    const int* ip = idxmat + (size_t)row * KNN;
    const float4 sc = ((const float4*)scv)[c4], sh = ((const float4*)shv)[c4];
    float4 m = {0.f, 0.f, 0.f, 0.f};
    #pragma unroll
    for (int k = 0; k < KNN; ++k) {
        const int j = ip[k];
        const float4 v = *(const float4*)(Hin + (size_t)j * 64 + c4 * 4);
        m.x = fmaxf(m.x, fmaf(v.x, sc.x, sh.x));
        m.y = fmaxf(m.y, fmaf(v.y, sc.y, sh.y));
        m.z = fmaxf(m.z, fmaf(v.z, sc.z, sh.z));
        m.w = fmaxf(m.w, fmaf(v.w, sc.w, sh.w));
    }
    ((float4*)(Z + (size_t)row * 64))[c4] = m;
}

// ---------- gather-max + BN(direct), 128 ch, split-bf16 out (+rawmax init) ----------
__global__ __launch_bounds__(256)
void gathermax_bn128_split(const float* __restrict__ Hin, const int* __restrict__ idxmat,
                           const float* __restrict__ scv, const float* __restrict__ shv,
                           unsigned short* __restrict__ Zhi, unsigned short* __restrict__ Zlo,
                           unsigned* __restrict__ rawmax)
{
    if (blockIdx.x < 32) rawmax[blockIdx.x * 256 + threadIdx.x] = 0u;
    const int c4 = threadIdx.x & 31, rr = threadIdx.x >> 5;
    const int row = (blockIdx.x << 3) + rr;
    const int* ip = idxmat + (size_t)row * KNN;
    const float4 sc = ((const float4*)scv)[c4], sh = ((const float4*)shv)[c4];
    float4 m = {0.f, 0.f, 0.f, 0.f};
    #pragma unroll
    for (int k = 0; k < KNN; ++k) {
        const int j = ip[k];
        const float4 v = *(const float4*)(Hin + (size_t)j * 128 + c4 * 4);
        m.x = fmaxf(m.x, fmaf(v.x, sc.x, sh.x));
        m.y = fmaxf(m.y, fmaf(v.y, sc.y, sh.y));
        m.z = fmaxf(m.z, fmaf(v.z, sc.z, sh.z));
        m.w = fmaxf(m.w, fmaf(v.w, sc.w, sh.w));
    }
    ushort4 hi, lo;
    hi.x = f2bf(m.x); lo.x = f2bf(m.x - bf2f(hi.x));
    hi.y = f2bf(m.y); lo.y = f2bf(m.y - bf2f(hi.y));
    hi.z = f2bf(m.z); lo.z = f2bf(m.z - bf2f(hi.z));
    hi.w = f2bf(m.w); lo.w = f2bf(m.w - bf2f(hi.w));
    *(ushort4*)(Zhi + (size_t)row * 128 + c4 * 4) = hi;
    *(ushort4*)(Zlo + (size_t)row * 128 + c4 * 4) = lo;
}

// ---------- head: 8-row GEMM + BN(8) + ReLU; 64 blocks x 8 cols, 32-way K-split ----------
template<int KDIM>
__global__ __launch_bounds__(256)
void mlp8_kernel(const float* __restrict__ In, const float* __restrict__ W,
                 const float* __restrict__ bias, const float* __restrict__ g,
                 const float* __restrict__ be, float* __restrict__ Out)
{
    __shared__ float Ins[8 * KDIM];
    __shared__ float part[32][8][8];
    __shared__ float ys[8][8];
    const int tid = threadIdx.x;
    for (int e = tid; e < 8 * KDIM; e += 256) Ins[e] = In[e];
    __syncthreads();
    const int c = tid & 7, kp = tid >> 3;
    const int col = (blockIdx.x << 3) + c;
    constexpr int KS = KDIM / 32;
    float a[8] = {};
    for (int k = kp * KS; k < (kp + 1) * KS; ++k) {
        const float w = W[(size_t)k * 512 + col];
        #pragma unroll
        for (int r = 0; r < 8; ++r) a[r] = fmaf(Ins[r * KDIM + k], w, a[r]);
    }
    #pragma unroll
    for (int r = 0; r < 8; ++r) part[kp][r][c] = a[r];
    __syncthreads();
    if (tid < 64) {
        const int r = tid >> 3, cc = tid & 7;
        float s = 0.f;
        #pragma unroll
        for (int p = 0; p < 32; ++p) s += part[p][r][cc];
        ys[r][cc] = s + bias[(blockIdx.x << 3) + cc];
    }
    __syncthreads();
    if (tid < 8) {
        const int c2 = (blockIdx.x << 3) + tid;
        float s = 0.f, ss = 0.f;
        #pragma unroll
        for (int r = 0; r < 8; ++r) { const float v = ys[r][tid]; s += v; ss = fmaf(v, v, ss); }
        const float mean = s * 0.125f;
        const float var = fmaxf(ss * 0.125f - mean * mean, 0.f);
        const float sc = g[c2] * rsqrtf(var + 1e-5f);
        const float sh = be[c2] - mean * sc;
        #pragma unroll
        for (int r = 0; r < 8; ++r)
            Out[r * 512 + c2] = fmaxf(0.f, fmaf(ys[r][tid], sc, sh));
    }
}

// ---------- launcher ----------
extern "C" void kernel_launch(void* const* d_in, const int* in_sizes, int n_in,
                              void* d_out, int out_size, void* d_ws, size_t ws_size,
                              hipStream_t stream)
{
    const float* x    = (const float*)d_in[0];
    const int*   mask = (const int*)d_in[1];
    const float* w_m1a = (const float*)d_in[2];
    const float* b_m1a = (const float*)d_in[3];
    const float* g_m1a = (const float*)d_in[4];
    const float* be_m1a = (const float*)d_in[5];
    const float* w_m1b = (const float*)d_in[6];
    const float* b_m1b = (const float*)d_in[7];
    const float* g_m1b = (const float*)d_in[8];
    const float* be_m1b = (const float*)d_in[9];
    const float* w_m1c = (const float*)d_in[10];
    const float* b_m1c = (const float*)d_in[11];
    const float* g_m1c = (const float*)d_in[12];
    const float* be_m1c = (const float*)d_in[13];
    const float* w_gl1 = (const float*)d_in[14];
    const float* b_gl1 = (const float*)d_in[15];
    const float* g_gl1 = (const float*)d_in[16];
    const float* be_gl1 = (const float*)d_in[17];
    const float* w_gl2 = (const float*)d_in[18];
    const float* b_gl2 = (const float*)d_in[19];
    const float* g_gl2 = (const float*)d_in[20];
    const float* be_gl2 = (const float*)d_in[21];
    const float* w_m2a = (const float*)d_in[22];
    const float* b_m2a = (const float*)d_in[23];
    const float* g_m2a = (const float*)d_in[24];
    const float* be_m2a = (const float*)d_in[25];
    const float* w_m2b = (const float*)d_in[26];
    const float* b_m2b = (const float*)d_in[27];
    const float* g_m2b = (const float*)d_in[28];
    const float* be_m2b = (const float*)d_in[29];

    float* ws = (float*)d_ws;
    int*   idx  = (int*)ws;                              // +262144
    float* h0   = ws + 262144;                           // +196608
    float* bufA = ws + 458752;                           // +1048576
    float* bufB = ws + 1507328;                          // +1048576
    float* bufC = ws + 2555904;                          // +2097152
    unsigned short* wTh = (unsigned short*)(ws + 4653056);   // +65536
    unsigned short* wTl = (unsigned short*)(ws + 4718592);   // +65536
    unsigned* rawmax = (unsigned*)(ws + 4784128);        // +8192
    float* pooled = ws + 4792320;                        // +8192
    float* y1     = ws + 4800512;                        // +4096
    float* ps0    = ws + 4804608;                        // +131072
    float* pss0   = ws + 4935680;                        // +131072
    float* ps1    = ws + 5066752;                        // +131072
    float* pss1   = ws + 5197824;                        // +131072
    float* scale  = ws + 5328896;                        // +1024
    float* shift  = ws + 5329920;                        // +1024

    unsigned short* Ahi = (unsigned short*)bufA;
    unsigned short* Alo = (unsigned short*)bufB;

    // knn (512-thread blocks) + folded w_gl2 conversion
    knn_cov_kernel<<<2304, 512, 0, stream>>>(x, mask, idx, h0, w_gl2, wTh, wTl);

    // m1a: 12 -> 64
    bgemm_kernel<12, 64><<<1024, 256, 0, stream>>>(
        h0, w_m1a, b_m1a, nullptr, nullptr, bufA, ps0, pss0);
    stats_final_t<64, 1024><<<16, 256, 0, stream>>>(ps0, pss0, g_m1a, be_m1a, scale, shift);

    // m1b: 64 -> 64 (bn_m1a folded at X load)
    bgemm_kernel<64, 64><<<1024, 256, 0, stream>>>(
        bufA, w_m1b, b_m1b, scale, shift, bufB, ps1, pss1);
    stats_final_t<64, 1024><<<16, 256, 0, stream>>>(ps1, pss1, g_m1b, be_m1b, scale, shift);

    // m1c: 64 -> 64 (bn_m1b folded)
    bgemm_kernel<64, 64><<<1024, 256, 0, stream>>>(
        bufB, w_m1c, b_m1c, scale, shift, bufA, ps0, pss0);
    stats_final_t<64, 1024><<<16, 256, 0, stream>>>(ps0, pss0, g_m1c, be_m1c, scale, shift);

    // gather-max 64 (bn_m1c direct)
    gathermax_bn64<<<1024, 256, 0, stream>>>(bufA, idx, scale, shift, bufB);

    // gl1: 64 -> 128
    bgemm_kernel<64, 128><<<1024, 256, 0, stream>>>(
        bufB, w_gl1, b_gl1, nullptr, nullptr, bufC, ps1, pss1);
    stats_final_t<128, 1024><<<32, 256, 0, stream>>>(ps1, pss1, g_gl1, be_gl1, scale, shift);

    // gather-max 128 (bn_gl1 direct) -> split-bf16 A; inits rawmax
    gathermax_bn128_split<<<2048, 256, 0, stream>>>(bufC, idx, scale, shift, Ahi, Alo, rawmax);

    // gl2: 128 -> 1024, split-bf16 MFMA + stats chunks + masked col-max (no Y)
    gemm_gl2_mfma<<<dim3(128, 8), 256, 0, stream>>>(Ahi, Alo, wTh, wTl, b_gl2, mask, rawmax, ps0, pss0);

    // gl2 bn finalize + pooled decode
    stats_pool_final<<<256, 256, 0, stream>>>(ps0, pss0, g_gl2, be_gl2, rawmax, pooled);

    // head
    mlp8_kernel<1024><<<64, 256, 0, stream>>>(pooled, w_m2a, b_m2a, g_m2a, be_m2a, y1);
    mlp8_kernel<512><<<64, 256, 0, stream>>>(y1, w_m2b, b_m2b, g_m2b, be_m2b, (float*)d_out);
}